// Round 5
// baseline (186.786 us; speedup 1.0000x reference)
//
#include <hip/hip_runtime.h>
#include <hip/hip_bf16.h>
#include <stdint.h>

#define NNODES  1000000
#define INDIM   128
#define HIDDIM  256
#define NCLSN   47
#define N0SZ    1171456
#define N1SZ    45056
#define N2SZ    4096
#define F0SZ    25
#define F1SZ    10

typedef __attribute__((ext_vector_type(8))) short short8;
typedef __attribute__((ext_vector_type(4))) float f32x4;

__device__ inline unsigned short f2bfu(float x) {
    union { __hip_bfloat16 h; unsigned short u; } cv;
    cv.h = __float2bfloat16(x);
    return cv.u;
}

__device__ inline float bfu2f(unsigned short u) {
    union { float f; unsigned int u; } cv;
    cv.u = ((unsigned int)u) << 16;
    return cv.f;
}

// async global->LDS DMA, 16B per lane. LDS dest must be wave-uniform base
// (HW writes base + lane*16); global src is per-lane.
__device__ inline void gload_lds16(const float* g, float* l) {
    __builtin_amdgcn_global_load_lds(
        (const __attribute__((address_space(1))) unsigned int*)g,
        (__attribute__((address_space(3))) unsigned int*)l,
        16, 0, 0);
}

// ---------------------------------------------------------------------------
// Kernel 1: weight prep — bf16, transposed to [N][K].
// ---------------------------------------------------------------------------
__global__ __launch_bounds__(256) void prep_w_kernel(
    const float* __restrict__ Wn0, const float* __restrict__ Wr0,
    const float* __restrict__ Wn1, const float* __restrict__ Wr1,
    __hip_bfloat16* __restrict__ W0T, __hip_bfloat16* __restrict__ W1T) {
    int tid = blockIdx.x * 256 + threadIdx.x;
    if (tid < 256 * 256) {
        int n = tid >> 8, k = tid & 255;
        float v = (k < INDIM) ? Wn0[(size_t)k * HIDDIM + n] : Wr0[(size_t)(k - INDIM) * HIDDIM + n];
        W0T[(size_t)n * 256 + k] = __float2bfloat16(v);
    }
    if (tid < 48 * 512) {
        int n = tid / 512, k = tid % 512;
        float v = 0.f;
        if (n < NCLSN) v = (k < HIDDIM) ? Wn1[(size_t)k * NCLSN + n] : Wr1[(size_t)(k - HIDDIM) * NCLSN + n];
        W1T[(size_t)n * 512 + k] = __float2bfloat16(v);
    }
}

// ---------------------------------------------------------------------------
// Kernel 2: FUSED layer 0, DMA-gather version. 8 dst rows/block, 256 thr.
//   Gather: 5 chunks x (8 rows x 5 neighbors), double-buffered SBUF via
//   global_load_lds (each instr stages 2 rows: 64 lanes x 16B). Counted
//   vmcnt(5) + raw s_barrier keeps next chunk's DMA in flight across the
//   barrier. Sum phase reads SBUF, accumulates 4 f32/thread.
//   GEMM: 4 waves, M=8 rows (A-tile rows 8..15 garbage, C rows >=8 dropped),
//   N=256, K=256 vs W0T (L2-hot). +bias, ReLU -> H bf16.
// LDS: SBUF 40KB + Atile 8.4KB + idx ~0.9KB ~= 50KB -> 3 blocks/CU.
// ---------------------------------------------------------------------------
__global__ __launch_bounds__(256) void fused_layer0_kernel(
    const float* __restrict__ node_feat, const int* __restrict__ gid0,
    const int* __restrict__ col0, const __hip_bfloat16* __restrict__ W0T,
    const float* __restrict__ b0, __hip_bfloat16* __restrict__ H) {
    __shared__ int sg[8 * F0SZ];
    __shared__ int sself[8];
    __shared__ alignas(16) float SBUF[2][8 * 5 * INDIM];   // 2 x 20 KB
    __shared__ alignas(16) short Atile[16 * 264];          // rows 8..15 unused

    const int tid = threadIdx.x;
    const int rowbase = blockIdx.x * 8;

    // ---- stage indices (200 sg entries, 256 threads: one pass) ----
    if (tid < 8 * F0SZ) {
        int i = rowbase + tid / F0SZ;
        int f = tid % F0SZ;
        sg[tid] = gid0[col0[(size_t)i * F0SZ + f]];
    }
    if (tid < 8) sself[tid] = gid0[rowbase + tid];
    __syncthreads();

    const int r = tid >> 5;        // dst row 0..7
    const int l = tid & 31;        // float4 index 0..31 (dims l*4..l*4+3)

    // self row load early (1 outstanding vmem; retires under first vmcnt wait)
    float4 sv = ((const float4*)(node_feat + (size_t)sself[r] * INDIM))[l];

    // ---- DMA issue helper: chunk c (neighbors c*5..c*5+4) -> SBUF[b] ----
    const int w    = tid >> 6;     // wave 0..3
    const int half = (tid >> 5) & 1;
    const int li   = tid & 31;
    #define ISSUE_CHUNK(c, b)                                                  \
        {                                                                      \
            _Pragma("unroll")                                                  \
            for (int i = 0; i < 5; ++i) {                                      \
                int q  = w * 10 + i * 2 + half;  /* staged row 0..39 */        \
                int rr = q / 5, fq = q % 5;                                    \
                const float* gp = node_feat +                                  \
                    (size_t)sg[rr * F0SZ + (c) * 5 + fq] * INDIM + li * 4;     \
                float* lp = &SBUF[b][(w * 10 + i * 2) * INDIM];                \
                gload_lds16(gp, lp);                                           \
            }                                                                  \
        }

    float a0 = 0.f, a1 = 0.f, a2 = 0.f, a3 = 0.f;

    ISSUE_CHUNK(0, 0);
    #pragma unroll
    for (int c = 0; c < 5; ++c) {
        if (c < 4) {
            ISSUE_CHUNK(c + 1, (c + 1) & 1);
            asm volatile("s_waitcnt vmcnt(5)" ::: "memory");   // chunk c done, c+1 in flight
        } else {
            asm volatile("s_waitcnt vmcnt(0)" ::: "memory");
        }
        __builtin_amdgcn_s_barrier();            // all waves' chunk-c DMA visible
        const float* bb = &SBUF[c & 1][0];
        #pragma unroll
        for (int fq = 0; fq < 5; ++fq) {
            float4 v = ((const float4*)(bb + (r * 5 + fq) * INDIM))[l];
            a0 += v.x; a1 += v.y; a2 += v.z; a3 += v.w;
        }
        asm volatile("s_waitcnt lgkmcnt(0)" ::: "memory");     // reads retired
        __builtin_amdgcn_s_barrier();            // protect buffer for next issue
    }

    // ---- write A-tile: mean (dims 0..127) | self (dims 128..255), bf16 ----
    {
        const float s = 1.0f / F0SZ;
        ushort4 m, se;
        m.x = f2bfu(a0 * s); m.y = f2bfu(a1 * s); m.z = f2bfu(a2 * s); m.w = f2bfu(a3 * s);
        se.x = f2bfu(sv.x); se.y = f2bfu(sv.y); se.z = f2bfu(sv.z); se.w = f2bfu(sv.w);
        *(ushort4*)&Atile[r * 264 + l * 4] = m;
        *(ushort4*)&Atile[r * 264 + 128 + l * 4] = se;
    }
    __syncthreads();

    // ---- MFMA GEMM: wave w covers N cols [w*64, w*64+64) ----
    {
        const int lane = tid & 63;
        const int l15 = lane & 15;
        const int g = lane >> 4;
        const int nbase = w * 64;
        const short* B = (const short*)W0T;
        f32x4 acc[4] = {};
        #pragma unroll
        for (int kk = 0; kk < 256; kk += 32) {
            const int ka = kk + g * 8;
            short8 a = *(const short8*)&Atile[l15 * 264 + ka];
            #pragma unroll
            for (int nt = 0; nt < 4; ++nt) {
                short8 b = *(const short8*)(B + (size_t)(nbase + nt * 16 + l15) * 256 + ka);
                acc[nt] = __builtin_amdgcn_mfma_f32_16x16x32_bf16(a, b, acc[nt], 0, 0, 0);
            }
        }
        if (g < 2) {   // C rows 0..7 valid (M=8)
            #pragma unroll
            for (int nt = 0; nt < 4; ++nt) {
                const int col = nbase + nt * 16 + l15;
                const float bias = b0[col];
                #pragma unroll
                for (int rr = 0; rr < 4; ++rr) {
                    const int orow = rowbase + g * 4 + rr;
                    float v = acc[nt][rr] + bias;
                    v = v > 0.f ? v : 0.f;
                    H[(size_t)orow * HIDDIM + col] = __float2bfloat16(v);
                }
            }
        }
    }
}

// ---------------------------------------------------------------------------
// Kernel 3: FUSED layer 1. 512 thr/block, 16 dst rows/block (256 blocks).
// ---------------------------------------------------------------------------
__global__ __launch_bounds__(512) void fused_layer1_kernel(
    const __hip_bfloat16* __restrict__ H, const int* __restrict__ col1,
    const __hip_bfloat16* __restrict__ W1T, const float* __restrict__ b1,
    float* __restrict__ out) {
    __shared__ int sc[16 * F1SZ];
    __shared__ alignas(16) short Xtile[16 * 520];
    __shared__ alignas(16) float red[8][16 * 48];

    const int tid = threadIdx.x;
    const int rowbase = blockIdx.x * 16;

    if (tid < 16 * F1SZ) {
        int i = rowbase + tid / F1SZ;
        int f = tid % F1SZ;
        sc[tid] = col1[(size_t)i * F1SZ + f];
    }
    __syncthreads();

    {
        const int r = tid >> 5;
        const int l = tid & 31;
        const unsigned short* Hs = (const unsigned short*)H;
        float a0 = 0.f, a1 = 0.f, a2 = 0.f, a3 = 0.f, a4 = 0.f, a5 = 0.f, a6 = 0.f, a7 = 0.f;
        #pragma unroll
        for (int f = 0; f < F1SZ; ++f) {
            const unsigned short* p = Hs + (size_t)sc[r * F1SZ + f] * HIDDIM + l * 8;
            ushort4 v0 = ((const ushort4*)p)[0];
            ushort4 v1 = ((const ushort4*)p)[1];
            a0 += bfu2f(v0.x); a1 += bfu2f(v0.y); a2 += bfu2f(v0.z); a3 += bfu2f(v0.w);
            a4 += bfu2f(v1.x); a5 += bfu2f(v1.y); a6 += bfu2f(v1.z); a7 += bfu2f(v1.w);
        }
        const float s = 1.0f / F1SZ;
        short8 m;
        m[0] = f2bfu(a0 * s); m[1] = f2bfu(a1 * s); m[2] = f2bfu(a2 * s); m[3] = f2bfu(a3 * s);
        m[4] = f2bfu(a4 * s); m[5] = f2bfu(a5 * s); m[6] = f2bfu(a6 * s); m[7] = f2bfu(a7 * s);
        *(short8*)&Xtile[r * 520 + l * 8] = m;
        short8 se = *(const short8*)((const short*)Hs + (size_t)(rowbase + r) * HIDDIM + l * 8);
        *(short8*)&Xtile[r * 520 + 256 + l * 8] = se;
    }
    __syncthreads();

    {
        const int wid = tid >> 6;
        const int lane = tid & 63;
        const int l15 = lane & 15;
        const int g = lane >> 4;
        const short* B = (const short*)W1T;
        f32x4 acc[3] = {};
        const int kbase = wid * 64;
        #pragma unroll
        for (int ks = 0; ks < 2; ++ks) {
            const int ka = kbase + ks * 32 + g * 8;
            short8 a = *(const short8*)&Xtile[l15 * 520 + ka];
            #pragma unroll
            for (int nt = 0; nt < 3; ++nt) {
                short8 b = *(const short8*)(B + (size_t)(nt * 16 + l15) * 512 + ka);
                acc[nt] = __builtin_amdgcn_mfma_f32_16x16x32_bf16(a, b, acc[nt], 0, 0, 0);
            }
        }
        #pragma unroll
        for (int nt = 0; nt < 3; ++nt)
            #pragma unroll
            for (int rr = 0; rr < 4; ++rr)
                red[wid][(g * 4 + rr) * 48 + nt * 16 + l15] = acc[nt][rr];
    }
    __syncthreads();

    for (int t = tid; t < 16 * 48; t += 512) {
        int rr = t / 48, c = t % 48;
        if (c < NCLSN) {
            float v = b1[c];
            #pragma unroll
            for (int w = 0; w < 8; ++w) v += red[w][t];
            out[(size_t)(rowbase + rr) * NCLSN + c] = v;
        }
    }
}

// ---------------------------------------------------------------------------
extern "C" void kernel_launch(void* const* d_in, const int* in_sizes, int n_in,
                              void* d_out, int out_size, void* d_ws, size_t ws_size,
                              hipStream_t stream) {
    const float* node_feat = (const float*)d_in[0];
    const int*   gid0      = (const int*)d_in[1];
    const int*   col0      = (const int*)d_in[2];
    const int*   col1      = (const int*)d_in[3];
    const float* Wn0       = (const float*)d_in[4];
    const float* Wr0       = (const float*)d_in[5];
    const float* b0        = (const float*)d_in[6];
    const float* Wn1       = (const float*)d_in[7];
    const float* Wr1       = (const float*)d_in[8];
    const float* b1        = (const float*)d_in[9];

    char* ws = (char*)d_ws;
    __hip_bfloat16* H   = (__hip_bfloat16*)(ws);
    __hip_bfloat16* W0T = (__hip_bfloat16*)(ws + 23068672);
    __hip_bfloat16* W1T = (__hip_bfloat16*)(ws + 23068672 + 131072);
    float* out = (float*)d_out;

    hipLaunchKernelGGL(prep_w_kernel, dim3(256), dim3(256), 0, stream,
                       Wn0, Wr0, Wn1, Wr1, W0T, W1T);
    hipLaunchKernelGGL(fused_layer0_kernel, dim3(N1SZ / 8), dim3(256), 0, stream,
                       node_feat, gid0, col0, W0T, b0, H);
    hipLaunchKernelGGL(fused_layer1_kernel, dim3(N2SZ / 16), dim3(512), 0, stream,
                       H, col1, W1T, b1, out);
}

// Round 6
// 139.181 us; speedup vs baseline: 1.3420x; 1.3420x over previous
//
#include <hip/hip_runtime.h>
#include <hip/hip_bf16.h>
#include <stdint.h>

#define NNODES  1000000
#define INDIM   128
#define HIDDIM  256
#define NCLSN   47
#define N0SZ    1171456
#define N1SZ    45056
#define N2SZ    4096
#define F0SZ    25
#define F1SZ    10

typedef __attribute__((ext_vector_type(8))) short short8;
typedef __attribute__((ext_vector_type(4))) float f32x4;

__device__ inline unsigned short f2bfu(float x) {
    union { __hip_bfloat16 h; unsigned short u; } cv;
    cv.h = __float2bfloat16(x);
    return cv.u;
}

__device__ inline float bfu2f(unsigned short u) {
    union { float f; unsigned int u; } cv;
    cv.u = ((unsigned int)u) << 16;
    return cv.f;
}

// ---------------------------------------------------------------------------
// Kernel 1: prep — weight transpose to bf16 [N][K]  +  flatten the two-level
// gather indices: fidx[e] = gid0[col0[e]] (so the hot kernel's staging is a
// single coalesced read), sidx[i] = gid0[i].
// grid = 4400 blocks x 256 = 1,126,400 threads (exactly N1*F0).
// ---------------------------------------------------------------------------
__global__ __launch_bounds__(256) void prep_kernel(
    const float* __restrict__ Wn0, const float* __restrict__ Wr0,
    const float* __restrict__ Wn1, const float* __restrict__ Wr1,
    const int* __restrict__ gid0, const int* __restrict__ col0,
    __hip_bfloat16* __restrict__ W0T, __hip_bfloat16* __restrict__ W1T,
    int* __restrict__ fidx, int* __restrict__ sidx) {
    const int tid = blockIdx.x * 256 + threadIdx.x;
    if (tid < 256 * 256) {
        int n = tid >> 8, k = tid & 255;
        float v = (k < INDIM) ? Wn0[(size_t)k * HIDDIM + n] : Wr0[(size_t)(k - INDIM) * HIDDIM + n];
        W0T[(size_t)n * 256 + k] = __float2bfloat16(v);
    }
    if (tid < 48 * 512) {
        int n = tid / 512, k = tid % 512;
        float v = 0.f;
        if (n < NCLSN) v = (k < HIDDIM) ? Wn1[(size_t)k * NCLSN + n] : Wr1[(size_t)(k - HIDDIM) * NCLSN + n];
        W1T[(size_t)n * 512 + k] = __float2bfloat16(v);
    }
    if (tid < N1SZ) sidx[tid] = gid0[tid];
    if (tid < N1SZ * F0SZ) fidx[tid] = gid0[col0[tid]];
}

// ---------------------------------------------------------------------------
// Kernel 2: FUSED layer 0 (round-4 structure — the 144 us winner).
// Per block: 16 dst rows, 256 threads.
//   phase A: stage 400 flat indices (coalesced from fidx); gather 16x25
//            neighbor rows (fp32, 512B) + 16 self rows, register-accumulate
//            (25 independent loads/thread -> compiler-pipelined MLP);
//            mean; bf16; LDS A-tile [16][264pad]
//            (cols 0..127 = mean -> Wn0 part; 128..255 = self -> Wr0 part)
//   phase B: 4-wave MFMA GEMM (M=16, N=256, K=256) vs W0T (L2-hot),
//            +bias, ReLU, write H bf16 [45056][256].
// ---------------------------------------------------------------------------
__global__ __launch_bounds__(256) void fused_layer0_kernel(
    const float* __restrict__ node_feat, const int* __restrict__ fidx,
    const int* __restrict__ sidx, const __hip_bfloat16* __restrict__ W0T,
    const float* __restrict__ b0, __hip_bfloat16* __restrict__ H) {
    __shared__ int sg[16 * F0SZ];
    __shared__ int sself[16];
    __shared__ alignas(16) short Atile[16 * 264];

    const int tid = threadIdx.x;
    const int rowbase = blockIdx.x * 16;

    // ---- stage flat indices (coalesced; 400 entries, stride loop) ----
    for (int t = tid; t < 16 * F0SZ; t += 256)
        sg[t] = fidx[(size_t)rowbase * F0SZ + t];
    if (tid < 16) sself[tid] = sidx[rowbase + tid];
    __syncthreads();

    // ---- gather + mean: 16 rows x 16 lanes, each lane 8 dims ----
    {
        const int r = tid >> 4;        // 0..15
        const int l = tid & 15;        // 0..15, covers dims [l*8, l*8+8)
        float a0 = 0.f, a1 = 0.f, a2 = 0.f, a3 = 0.f, a4 = 0.f, a5 = 0.f, a6 = 0.f, a7 = 0.f;
        #pragma unroll
        for (int f = 0; f < F0SZ; ++f) {
            const float* p = node_feat + (size_t)sg[r * F0SZ + f] * INDIM + l * 8;
            float4 v0 = ((const float4*)p)[0];
            float4 v1 = ((const float4*)p)[1];
            a0 += v0.x; a1 += v0.y; a2 += v0.z; a3 += v0.w;
            a4 += v1.x; a5 += v1.y; a6 += v1.z; a7 += v1.w;
        }
        const float s = 1.0f / F0SZ;
        short8 m;
        m[0] = f2bfu(a0 * s); m[1] = f2bfu(a1 * s); m[2] = f2bfu(a2 * s); m[3] = f2bfu(a3 * s);
        m[4] = f2bfu(a4 * s); m[5] = f2bfu(a5 * s); m[6] = f2bfu(a6 * s); m[7] = f2bfu(a7 * s);
        *(short8*)&Atile[r * 264 + l * 8] = m;

        const float* sp = node_feat + (size_t)sself[r] * INDIM + l * 8;
        float4 s0 = ((const float4*)sp)[0];
        float4 s1 = ((const float4*)sp)[1];
        short8 se;
        se[0] = f2bfu(s0.x); se[1] = f2bfu(s0.y); se[2] = f2bfu(s0.z); se[3] = f2bfu(s0.w);
        se[4] = f2bfu(s1.x); se[5] = f2bfu(s1.y); se[6] = f2bfu(s1.z); se[7] = f2bfu(s1.w);
        *(short8*)&Atile[r * 264 + 128 + l * 8] = se;
    }
    __syncthreads();

    // ---- MFMA GEMM: wave w covers N cols [w*64, w*64+64) ----
    {
        const int wid = tid >> 6;
        const int lane = tid & 63;
        const int l15 = lane & 15;
        const int g = lane >> 4;
        const int nbase = wid * 64;
        const short* B = (const short*)W0T;
        f32x4 acc[4] = {};
        #pragma unroll
        for (int kk = 0; kk < 256; kk += 32) {
            const int ka = kk + g * 8;
            short8 a = *(const short8*)&Atile[l15 * 264 + ka];
            #pragma unroll
            for (int nt = 0; nt < 4; ++nt) {
                short8 b = *(const short8*)(B + (size_t)(nbase + nt * 16 + l15) * 256 + ka);
                acc[nt] = __builtin_amdgcn_mfma_f32_16x16x32_bf16(a, b, acc[nt], 0, 0, 0);
            }
        }
        #pragma unroll
        for (int nt = 0; nt < 4; ++nt) {
            const int col = nbase + nt * 16 + l15;
            const float bias = b0[col];
            #pragma unroll
            for (int r = 0; r < 4; ++r) {
                const int rr = rowbase + g * 4 + r;
                float v = acc[nt][r] + bias;
                v = v > 0.f ? v : 0.f;
                H[(size_t)rr * HIDDIM + col] = __float2bfloat16(v);
            }
        }
    }
}

// ---------------------------------------------------------------------------
// Kernel 3: FUSED layer 1 (unchanged from round-4). 512 thr/block,
// 16 dst rows/block (256 blocks).
// ---------------------------------------------------------------------------
__global__ __launch_bounds__(512) void fused_layer1_kernel(
    const __hip_bfloat16* __restrict__ H, const int* __restrict__ col1,
    const __hip_bfloat16* __restrict__ W1T, const float* __restrict__ b1,
    float* __restrict__ out) {
    __shared__ int sc[16 * F1SZ];
    __shared__ alignas(16) short Xtile[16 * 520];
    __shared__ alignas(16) float red[8][16 * 48];

    const int tid = threadIdx.x;
    const int rowbase = blockIdx.x * 16;

    if (tid < 16 * F1SZ) {
        int i = rowbase + tid / F1SZ;
        int f = tid % F1SZ;
        sc[tid] = col1[(size_t)i * F1SZ + f];
    }
    __syncthreads();

    {
        const int r = tid >> 5;
        const int l = tid & 31;
        const unsigned short* Hs = (const unsigned short*)H;
        float a0 = 0.f, a1 = 0.f, a2 = 0.f, a3 = 0.f, a4 = 0.f, a5 = 0.f, a6 = 0.f, a7 = 0.f;
        #pragma unroll
        for (int f = 0; f < F1SZ; ++f) {
            const unsigned short* p = Hs + (size_t)sc[r * F1SZ + f] * HIDDIM + l * 8;
            ushort4 v0 = ((const ushort4*)p)[0];
            ushort4 v1 = ((const ushort4*)p)[1];
            a0 += bfu2f(v0.x); a1 += bfu2f(v0.y); a2 += bfu2f(v0.z); a3 += bfu2f(v0.w);
            a4 += bfu2f(v1.x); a5 += bfu2f(v1.y); a6 += bfu2f(v1.z); a7 += bfu2f(v1.w);
        }
        const float s = 1.0f / F1SZ;
        short8 m;
        m[0] = f2bfu(a0 * s); m[1] = f2bfu(a1 * s); m[2] = f2bfu(a2 * s); m[3] = f2bfu(a3 * s);
        m[4] = f2bfu(a4 * s); m[5] = f2bfu(a5 * s); m[6] = f2bfu(a6 * s); m[7] = f2bfu(a7 * s);
        *(short8*)&Xtile[r * 520 + l * 8] = m;
        short8 se = *(const short8*)((const short*)Hs + (size_t)(rowbase + r) * HIDDIM + l * 8);
        *(short8*)&Xtile[r * 520 + 256 + l * 8] = se;
    }
    __syncthreads();

    {
        const int wid = tid >> 6;
        const int lane = tid & 63;
        const int l15 = lane & 15;
        const int g = lane >> 4;
        const short* B = (const short*)W1T;
        f32x4 acc[3] = {};
        const int kbase = wid * 64;
        #pragma unroll
        for (int ks = 0; ks < 2; ++ks) {
            const int ka = kbase + ks * 32 + g * 8;
            short8 a = *(const short8*)&Xtile[l15 * 520 + ka];
            #pragma unroll
            for (int nt = 0; nt < 3; ++nt) {
                short8 b = *(const short8*)(B + (size_t)(nt * 16 + l15) * 512 + ka);
                acc[nt] = __builtin_amdgcn_mfma_f32_16x16x32_bf16(a, b, acc[nt], 0, 0, 0);
            }
        }
        #pragma unroll
        for (int nt = 0; nt < 3; ++nt)
            #pragma unroll
            for (int rr = 0; rr < 4; ++rr)
                red[wid][(g * 4 + rr) * 48 + nt * 16 + l15] = acc[nt][rr];
    }
    __syncthreads();

    for (int t = tid; t < 16 * 48; t += 512) {
        int rr = t / 48, c = t % 48;
        if (c < NCLSN) {
            float v = b1[c];
            #pragma unroll
            for (int w = 0; w < 8; ++w) v += red[w][t];
            out[(size_t)(rowbase + rr) * NCLSN + c] = v;
        }
    }
}

// ---------------------------------------------------------------------------
extern "C" void kernel_launch(void* const* d_in, const int* in_sizes, int n_in,
                              void* d_out, int out_size, void* d_ws, size_t ws_size,
                              hipStream_t stream) {
    const float* node_feat = (const float*)d_in[0];
    const int*   gid0      = (const int*)d_in[1];
    const int*   col0      = (const int*)d_in[2];
    const int*   col1      = (const int*)d_in[3];
    const float* Wn0       = (const float*)d_in[4];
    const float* Wr0       = (const float*)d_in[5];
    const float* b0        = (const float*)d_in[6];
    const float* Wn1       = (const float*)d_in[7];
    const float* Wr1       = (const float*)d_in[8];
    const float* b1        = (const float*)d_in[9];

    char* ws = (char*)d_ws;
    // ws layout:
    //   H    bf16 [45056][256] : 23,068,672
    //   W0T  bf16 [256][256]   :    131,072   @ 23,068,672
    //   W1T  bf16 [48][512]    :     49,152   @ 23,199,744
    //   fidx int  [1,126,400]  :  4,505,600   @ 23,248,896
    //   sidx int  [45,056]     :    180,224   @ 27,754,496
    __hip_bfloat16* H   = (__hip_bfloat16*)(ws);
    __hip_bfloat16* W0T = (__hip_bfloat16*)(ws + 23068672);
    __hip_bfloat16* W1T = (__hip_bfloat16*)(ws + 23199744);
    int*            fidx = (int*)(ws + 23248896);
    int*            sidx = (int*)(ws + 27754496);
    float* out = (float*)d_out;

    hipLaunchKernelGGL(prep_kernel, dim3(4400), dim3(256), 0, stream,
                       Wn0, Wr0, Wn1, Wr1, gid0, col0, W0T, W1T, fidx, sidx);
    hipLaunchKernelGGL(fused_layer0_kernel, dim3(N1SZ / 16), dim3(256), 0, stream,
                       node_feat, fidx, sidx, W0T, b0, H);
    hipLaunchKernelGGL(fused_layer1_kernel, dim3(N2SZ / 16), dim3(512), 0, stream,
                       H, col1, W1T, b1, out);
}

// Round 7
// 116.235 us; speedup vs baseline: 1.6070x; 1.1974x over previous
//
#include <hip/hip_runtime.h>
#include <hip/hip_bf16.h>
#include <stdint.h>

#define NNODES  1000000
#define INDIM   128
#define HIDDIM  256
#define NCLSN   47
#define N0SZ    1171456
#define N1SZ    45056
#define N2SZ    4096
#define F0SZ    25
#define F1SZ    10

typedef __attribute__((ext_vector_type(8))) short short8;
typedef __attribute__((ext_vector_type(4))) float f32x4;

__device__ inline unsigned short f2bfu(float x) {
    union { __hip_bfloat16 h; unsigned short u; } cv;
    cv.h = __float2bfloat16(x);
    return cv.u;
}

__device__ inline float bfu2f(unsigned short u) {
    union { float f; unsigned int u; } cv;
    cv.u = ((unsigned int)u) << 16;
    return cv.f;
}

// ---------------------------------------------------------------------------
// Kernel 1: prep — weight transpose to bf16 [N][K]; flatten two-level gather
// indices (fidx[e] = gid0[col0[e]], sidx[i] = gid0[i]); init needed-row mask
// (self rows [0,4096) needed, rest 0 — mark_kernel fills in col1 rows).
// ---------------------------------------------------------------------------
__global__ __launch_bounds__(256) void prep_kernel(
    const float* __restrict__ Wn0, const float* __restrict__ Wr0,
    const float* __restrict__ Wn1, const float* __restrict__ Wr1,
    const int* __restrict__ gid0, const int* __restrict__ col0,
    __hip_bfloat16* __restrict__ W0T, __hip_bfloat16* __restrict__ W1T,
    int* __restrict__ fidx, int* __restrict__ sidx, int* __restrict__ mask) {
    const int tid = blockIdx.x * 256 + threadIdx.x;
    if (tid < 256 * 256) {
        int n = tid >> 8, k = tid & 255;
        float v = (k < INDIM) ? Wn0[(size_t)k * HIDDIM + n] : Wr0[(size_t)(k - INDIM) * HIDDIM + n];
        W0T[(size_t)n * 256 + k] = __float2bfloat16(v);
    }
    if (tid < 48 * 512) {
        int n = tid / 512, k = tid % 512;
        float v = 0.f;
        if (n < NCLSN) v = (k < HIDDIM) ? Wn1[(size_t)k * NCLSN + n] : Wr1[(size_t)(k - HIDDIM) * NCLSN + n];
        W1T[(size_t)n * 512 + k] = __float2bfloat16(v);
    }
    if (tid < N1SZ) {
        sidx[tid] = gid0[tid];
        mask[tid] = (tid < N2SZ) ? 1 : 0;
    }
    if (tid < N1SZ * F0SZ) fidx[tid] = gid0[col0[tid]];
}

// ---------------------------------------------------------------------------
// Kernel 1b: mark H rows referenced by layer-1 neighbors (all lanes write 1 —
// race-benign). Must run after prep_kernel (stream-ordered).
// ---------------------------------------------------------------------------
__global__ __launch_bounds__(256) void mark_kernel(
    const int* __restrict__ col1, int* __restrict__ mask) {
    const int t = blockIdx.x * 256 + threadIdx.x;
    if (t < N2SZ * F1SZ) mask[col1[t]] = 1;
}

// ---------------------------------------------------------------------------
// Kernel 2: FUSED layer 0 with dead-row elimination.
// Per block: 16 dst rows, 256 threads. Rows with mask==0 skip the entire
// 25-neighbor gather + self load + H store (their A-tile rows are zeros).
// ---------------------------------------------------------------------------
__global__ __launch_bounds__(256) void fused_layer0_kernel(
    const float* __restrict__ node_feat, const int* __restrict__ fidx,
    const int* __restrict__ sidx, const int* __restrict__ mask,
    const __hip_bfloat16* __restrict__ W0T, const float* __restrict__ b0,
    __hip_bfloat16* __restrict__ H) {
    __shared__ int sg[16 * F0SZ];
    __shared__ int sself[16];
    __shared__ int smask[16];
    __shared__ alignas(16) short Atile[16 * 264];

    const int tid = threadIdx.x;
    const int rowbase = blockIdx.x * 16;

    // ---- stage flat indices (coalesced) + per-row mask ----
    for (int t = tid; t < 16 * F0SZ; t += 256)
        sg[t] = fidx[(size_t)rowbase * F0SZ + t];
    if (tid < 16) {
        sself[tid] = sidx[rowbase + tid];
        smask[tid] = mask[rowbase + tid];
    }
    __syncthreads();

    // ---- gather + mean: 16 rows x 16 lanes, each lane 8 dims ----
    {
        const int r = tid >> 4;        // 0..15
        const int l = tid & 15;        // 0..15, covers dims [l*8, l*8+8)
        float a0 = 0.f, a1 = 0.f, a2 = 0.f, a3 = 0.f, a4 = 0.f, a5 = 0.f, a6 = 0.f, a7 = 0.f;
        float4 s0 = make_float4(0.f, 0.f, 0.f, 0.f);
        float4 s1 = make_float4(0.f, 0.f, 0.f, 0.f);
        if (smask[r]) {
            #pragma unroll
            for (int f = 0; f < F0SZ; ++f) {
                const float* p = node_feat + (size_t)sg[r * F0SZ + f] * INDIM + l * 8;
                float4 v0 = ((const float4*)p)[0];
                float4 v1 = ((const float4*)p)[1];
                a0 += v0.x; a1 += v0.y; a2 += v0.z; a3 += v0.w;
                a4 += v1.x; a5 += v1.y; a6 += v1.z; a7 += v1.w;
            }
            const float* sp = node_feat + (size_t)sself[r] * INDIM + l * 8;
            s0 = ((const float4*)sp)[0];
            s1 = ((const float4*)sp)[1];
        }
        const float s = 1.0f / F0SZ;
        short8 m;
        m[0] = f2bfu(a0 * s); m[1] = f2bfu(a1 * s); m[2] = f2bfu(a2 * s); m[3] = f2bfu(a3 * s);
        m[4] = f2bfu(a4 * s); m[5] = f2bfu(a5 * s); m[6] = f2bfu(a6 * s); m[7] = f2bfu(a7 * s);
        *(short8*)&Atile[r * 264 + l * 8] = m;
        short8 se;
        se[0] = f2bfu(s0.x); se[1] = f2bfu(s0.y); se[2] = f2bfu(s0.z); se[3] = f2bfu(s0.w);
        se[4] = f2bfu(s1.x); se[5] = f2bfu(s1.y); se[6] = f2bfu(s1.z); se[7] = f2bfu(s1.w);
        *(short8*)&Atile[r * 264 + 128 + l * 8] = se;
    }
    __syncthreads();

    // ---- MFMA GEMM: wave w covers N cols [w*64, w*64+64) ----
    {
        const int wid = tid >> 6;
        const int lane = tid & 63;
        const int l15 = lane & 15;
        const int g = lane >> 4;
        const int nbase = wid * 64;
        const short* B = (const short*)W0T;
        f32x4 acc[4] = {};
        #pragma unroll
        for (int kk = 0; kk < 256; kk += 32) {
            const int ka = kk + g * 8;
            short8 a = *(const short8*)&Atile[l15 * 264 + ka];
            #pragma unroll
            for (int nt = 0; nt < 4; ++nt) {
                short8 b = *(const short8*)(B + (size_t)(nbase + nt * 16 + l15) * 256 + ka);
                acc[nt] = __builtin_amdgcn_mfma_f32_16x16x32_bf16(a, b, acc[nt], 0, 0, 0);
            }
        }
        #pragma unroll
        for (int nt = 0; nt < 4; ++nt) {
            const int col = nbase + nt * 16 + l15;
            const float bias = b0[col];
            #pragma unroll
            for (int r = 0; r < 4; ++r) {
                if (smask[g * 4 + r]) {
                    const int rr = rowbase + g * 4 + r;
                    float v = acc[nt][r] + bias;
                    v = v > 0.f ? v : 0.f;
                    H[(size_t)rr * HIDDIM + col] = __float2bfloat16(v);
                }
            }
        }
    }
}

// ---------------------------------------------------------------------------
// Kernel 3: FUSED layer 1 (unchanged). 512 thr/block, 16 dst rows/block.
// ---------------------------------------------------------------------------
__global__ __launch_bounds__(512) void fused_layer1_kernel(
    const __hip_bfloat16* __restrict__ H, const int* __restrict__ col1,
    const __hip_bfloat16* __restrict__ W1T, const float* __restrict__ b1,
    float* __restrict__ out) {
    __shared__ int sc[16 * F1SZ];
    __shared__ alignas(16) short Xtile[16 * 520];
    __shared__ alignas(16) float red[8][16 * 48];

    const int tid = threadIdx.x;
    const int rowbase = blockIdx.x * 16;

    if (tid < 16 * F1SZ) {
        int i = rowbase + tid / F1SZ;
        int f = tid % F1SZ;
        sc[tid] = col1[(size_t)i * F1SZ + f];
    }
    __syncthreads();

    {
        const int r = tid >> 5;
        const int l = tid & 31;
        const unsigned short* Hs = (const unsigned short*)H;
        float a0 = 0.f, a1 = 0.f, a2 = 0.f, a3 = 0.f, a4 = 0.f, a5 = 0.f, a6 = 0.f, a7 = 0.f;
        #pragma unroll
        for (int f = 0; f < F1SZ; ++f) {
            const unsigned short* p = Hs + (size_t)sc[r * F1SZ + f] * HIDDIM + l * 8;
            ushort4 v0 = ((const ushort4*)p)[0];
            ushort4 v1 = ((const ushort4*)p)[1];
            a0 += bfu2f(v0.x); a1 += bfu2f(v0.y); a2 += bfu2f(v0.z); a3 += bfu2f(v0.w);
            a4 += bfu2f(v1.x); a5 += bfu2f(v1.y); a6 += bfu2f(v1.z); a7 += bfu2f(v1.w);
        }
        const float s = 1.0f / F1SZ;
        short8 m;
        m[0] = f2bfu(a0 * s); m[1] = f2bfu(a1 * s); m[2] = f2bfu(a2 * s); m[3] = f2bfu(a3 * s);
        m[4] = f2bfu(a4 * s); m[5] = f2bfu(a5 * s); m[6] = f2bfu(a6 * s); m[7] = f2bfu(a7 * s);
        *(short8*)&Xtile[r * 520 + l * 8] = m;
        short8 se = *(const short8*)((const short*)Hs + (size_t)(rowbase + r) * HIDDIM + l * 8);
        *(short8*)&Xtile[r * 520 + 256 + l * 8] = se;
    }
    __syncthreads();

    {
        const int wid = tid >> 6;
        const int lane = tid & 63;
        const int l15 = lane & 15;
        const int g = lane >> 4;
        const short* B = (const short*)W1T;
        f32x4 acc[3] = {};
        const int kbase = wid * 64;
        #pragma unroll
        for (int ks = 0; ks < 2; ++ks) {
            const int ka = kbase + ks * 32 + g * 8;
            short8 a = *(const short8*)&Xtile[l15 * 520 + ka];
            #pragma unroll
            for (int nt = 0; nt < 3; ++nt) {
                short8 b = *(const short8*)(B + (size_t)(nt * 16 + l15) * 512 + ka);
                acc[nt] = __builtin_amdgcn_mfma_f32_16x16x32_bf16(a, b, acc[nt], 0, 0, 0);
            }
        }
        #pragma unroll
        for (int nt = 0; nt < 3; ++nt)
            #pragma unroll
            for (int rr = 0; rr < 4; ++rr)
                red[wid][(g * 4 + rr) * 48 + nt * 16 + l15] = acc[nt][rr];
    }
    __syncthreads();

    for (int t = tid; t < 16 * 48; t += 512) {
        int rr = t / 48, c = t % 48;
        if (c < NCLSN) {
            float v = b1[c];
            #pragma unroll
            for (int w = 0; w < 8; ++w) v += red[w][t];
            out[(size_t)(rowbase + rr) * NCLSN + c] = v;
        }
    }
}

// ---------------------------------------------------------------------------
extern "C" void kernel_launch(void* const* d_in, const int* in_sizes, int n_in,
                              void* d_out, int out_size, void* d_ws, size_t ws_size,
                              hipStream_t stream) {
    const float* node_feat = (const float*)d_in[0];
    const int*   gid0      = (const int*)d_in[1];
    const int*   col0      = (const int*)d_in[2];
    const int*   col1      = (const int*)d_in[3];
    const float* Wn0       = (const float*)d_in[4];
    const float* Wr0       = (const float*)d_in[5];
    const float* b0        = (const float*)d_in[6];
    const float* Wn1       = (const float*)d_in[7];
    const float* Wr1       = (const float*)d_in[8];
    const float* b1        = (const float*)d_in[9];

    char* ws = (char*)d_ws;
    // ws layout:
    //   H    bf16 [45056][256] : 23,068,672
    //   W0T  bf16 [256][256]   :    131,072   @ 23,068,672
    //   W1T  bf16 [48][512]    :     49,152   @ 23,199,744
    //   fidx int  [1,126,400]  :  4,505,600   @ 23,248,896
    //   sidx int  [45,056]     :    180,224   @ 27,754,496
    //   mask int  [45,056]     :    180,224   @ 27,934,720
    __hip_bfloat16* H   = (__hip_bfloat16*)(ws);
    __hip_bfloat16* W0T = (__hip_bfloat16*)(ws + 23068672);
    __hip_bfloat16* W1T = (__hip_bfloat16*)(ws + 23199744);
    int*            fidx = (int*)(ws + 23248896);
    int*            sidx = (int*)(ws + 27754496);
    int*            mask = (int*)(ws + 27934720);
    float* out = (float*)d_out;

    hipLaunchKernelGGL(prep_kernel, dim3(4400), dim3(256), 0, stream,
                       Wn0, Wr0, Wn1, Wr1, gid0, col0, W0T, W1T, fidx, sidx, mask);
    hipLaunchKernelGGL(mark_kernel, dim3((N2SZ * F1SZ + 255) / 256), dim3(256), 0, stream,
                       col1, mask);
    hipLaunchKernelGGL(fused_layer0_kernel, dim3(N1SZ / 16), dim3(256), 0, stream,
                       node_feat, fidx, sidx, mask, W0T, b0, H);
    hipLaunchKernelGGL(fused_layer1_kernel, dim3(N2SZ / 16), dim3(512), 0, stream,
                       H, col1, W1T, b1, out);
}

// Round 8
// 111.033 us; speedup vs baseline: 1.6823x; 1.0469x over previous
//
#include <hip/hip_runtime.h>
#include <hip/hip_bf16.h>
#include <stdint.h>

#define NNODES  1000000
#define INDIM   128
#define HIDDIM  256
#define NCLSN   47
#define N0SZ    1171456
#define N1SZ    45056
#define N2SZ    4096
#define F0SZ    25
#define F1SZ    10

typedef __attribute__((ext_vector_type(8))) short short8;
typedef __attribute__((ext_vector_type(4))) float f32x4;

__device__ inline unsigned short f2bfu(float x) {
    union { __hip_bfloat16 h; unsigned short u; } cv;
    cv.h = __float2bfloat16(x);
    return cv.u;
}

__device__ inline float bfu2f(unsigned short u) {
    union { float f; unsigned int u; } cv;
    cv.u = ((unsigned int)u) << 16;
    return cv.f;
}

// ---------------------------------------------------------------------------
// Kernel 1: prep — weight transpose to bf16 [N][K]; flatten two-level gather
// indices (fidx[e] = gid0[col0[e]], sidx[i] = gid0[i]); seed live-row
// structures: mask[i]=(i<4096), list[0..4096)=identity, nlive=4096.
// ---------------------------------------------------------------------------
__global__ __launch_bounds__(256) void prep_kernel(
    const float* __restrict__ Wn0, const float* __restrict__ Wr0,
    const float* __restrict__ Wn1, const float* __restrict__ Wr1,
    const int* __restrict__ gid0, const int* __restrict__ col0,
    __hip_bfloat16* __restrict__ W0T, __hip_bfloat16* __restrict__ W1T,
    int* __restrict__ fidx, int* __restrict__ sidx,
    int* __restrict__ mask, int* __restrict__ list, int* __restrict__ nlive) {
    const int tid = blockIdx.x * 256 + threadIdx.x;
    if (tid < 256 * 256) {
        int n = tid >> 8, k = tid & 255;
        float v = (k < INDIM) ? Wn0[(size_t)k * HIDDIM + n] : Wr0[(size_t)(k - INDIM) * HIDDIM + n];
        W0T[(size_t)n * 256 + k] = __float2bfloat16(v);
    }
    if (tid < 48 * 512) {
        int n = tid / 512, k = tid % 512;
        float v = 0.f;
        if (n < NCLSN) v = (k < HIDDIM) ? Wn1[(size_t)k * NCLSN + n] : Wr1[(size_t)(k - HIDDIM) * NCLSN + n];
        W1T[(size_t)n * 512 + k] = __float2bfloat16(v);
    }
    if (tid < N1SZ) {
        sidx[tid] = gid0[tid];
        mask[tid] = (tid < N2SZ) ? 1 : 0;
    }
    if (tid < N2SZ) list[tid] = tid;
    if (tid == 0) *nlive = N2SZ;
    if (tid < N1SZ * F0SZ) fidx[tid] = gid0[col0[tid]];
}

// ---------------------------------------------------------------------------
// Kernel 1b: dedup-append H rows referenced by layer-1 neighbors.
// atomicExch on mask dedups; winner appends row id to list. List order is
// nondeterministic but per-row outputs are order-independent -> d_out exact.
// ---------------------------------------------------------------------------
__global__ __launch_bounds__(256) void mark_kernel(
    const int* __restrict__ col1, int* __restrict__ mask,
    int* __restrict__ list, int* __restrict__ nlive) {
    const int t = blockIdx.x * 256 + threadIdx.x;
    if (t < N2SZ * F1SZ) {
        int c = col1[t];
        if (atomicExch(&mask[c], 1) == 0) {
            int k = atomicAdd(nlive, 1);
            list[k] = c;
        }
    }
}

// ---------------------------------------------------------------------------
// Kernel 2: FUSED layer 0 over COMPACTED live rows.
// Per block: 16 live rows from list[rowbase..rowbase+16), 256 threads.
// Blocks with rowbase >= nlive return immediately. Tiles are 100% live
// (tail block may be partial). Gather/mean -> bf16 A-tile -> 4-wave MFMA
// vs W0T -> +bias, ReLU -> H rows at their ORIGINAL indices.
// ---------------------------------------------------------------------------
__global__ __launch_bounds__(256) void fused_layer0_kernel(
    const float* __restrict__ node_feat, const int* __restrict__ fidx,
    const int* __restrict__ sidx, const int* __restrict__ list,
    const int* __restrict__ nlive, const __hip_bfloat16* __restrict__ W0T,
    const float* __restrict__ b0, __hip_bfloat16* __restrict__ H) {
    __shared__ int sg[16 * F0SZ];
    __shared__ int sself[16];
    __shared__ int slist[16];
    __shared__ alignas(16) short Atile[16 * 264];

    const int tid = threadIdx.x;
    const int rowbase = blockIdx.x * 16;
    const int nl = *nlive;
    if (rowbase >= nl) return;

    // ---- stage row ids + flat indices (list/fidx are L2-hot) ----
    if (tid < 16) {
        int idx = rowbase + tid;
        int row = (idx < nl) ? list[idx] : -1;
        slist[tid] = row;
        sself[tid] = (row >= 0) ? sidx[row] : 0;
    }
    for (int t = tid; t < 16 * F0SZ; t += 256) {
        int idx = rowbase + t / F0SZ;
        sg[t] = (idx < nl) ? fidx[(size_t)list[idx] * F0SZ + t % F0SZ] : 0;
    }
    __syncthreads();

    // ---- gather + mean: 16 rows x 16 lanes, each lane 8 dims ----
    {
        const int r = tid >> 4;        // 0..15
        const int l = tid & 15;        // 0..15, covers dims [l*8, l*8+8)
        const bool live = (slist[r] >= 0);
        float a0 = 0.f, a1 = 0.f, a2 = 0.f, a3 = 0.f, a4 = 0.f, a5 = 0.f, a6 = 0.f, a7 = 0.f;
        float4 s0 = make_float4(0.f, 0.f, 0.f, 0.f);
        float4 s1 = make_float4(0.f, 0.f, 0.f, 0.f);
        if (live) {
            #pragma unroll
            for (int f = 0; f < F0SZ; ++f) {
                const float* p = node_feat + (size_t)sg[r * F0SZ + f] * INDIM + l * 8;
                float4 v0 = ((const float4*)p)[0];
                float4 v1 = ((const float4*)p)[1];
                a0 += v0.x; a1 += v0.y; a2 += v0.z; a3 += v0.w;
                a4 += v1.x; a5 += v1.y; a6 += v1.z; a7 += v1.w;
            }
            const float* sp = node_feat + (size_t)sself[r] * INDIM + l * 8;
            s0 = ((const float4*)sp)[0];
            s1 = ((const float4*)sp)[1];
        }
        const float s = 1.0f / F0SZ;
        short8 m;
        m[0] = f2bfu(a0 * s); m[1] = f2bfu(a1 * s); m[2] = f2bfu(a2 * s); m[3] = f2bfu(a3 * s);
        m[4] = f2bfu(a4 * s); m[5] = f2bfu(a5 * s); m[6] = f2bfu(a6 * s); m[7] = f2bfu(a7 * s);
        *(short8*)&Atile[r * 264 + l * 8] = m;
        short8 se;
        se[0] = f2bfu(s0.x); se[1] = f2bfu(s0.y); se[2] = f2bfu(s0.z); se[3] = f2bfu(s0.w);
        se[4] = f2bfu(s1.x); se[5] = f2bfu(s1.y); se[6] = f2bfu(s1.z); se[7] = f2bfu(s1.w);
        *(short8*)&Atile[r * 264 + 128 + l * 8] = se;
    }
    __syncthreads();

    // ---- MFMA GEMM: wave w covers N cols [w*64, w*64+64) ----
    {
        const int wid = tid >> 6;
        const int lane = tid & 63;
        const int l15 = lane & 15;
        const int g = lane >> 4;
        const int nbase = wid * 64;
        const short* B = (const short*)W0T;
        f32x4 acc[4] = {};
        #pragma unroll
        for (int kk = 0; kk < 256; kk += 32) {
            const int ka = kk + g * 8;
            short8 a = *(const short8*)&Atile[l15 * 264 + ka];
            #pragma unroll
            for (int nt = 0; nt < 4; ++nt) {
                short8 b = *(const short8*)(B + (size_t)(nbase + nt * 16 + l15) * 256 + ka);
                acc[nt] = __builtin_amdgcn_mfma_f32_16x16x32_bf16(a, b, acc[nt], 0, 0, 0);
            }
        }
        #pragma unroll
        for (int nt = 0; nt < 4; ++nt) {
            const int col = nbase + nt * 16 + l15;
            const float bias = b0[col];
            #pragma unroll
            for (int r = 0; r < 4; ++r) {
                const int row = slist[g * 4 + r];
                if (row >= 0) {
                    float v = acc[nt][r] + bias;
                    v = v > 0.f ? v : 0.f;
                    H[(size_t)row * HIDDIM + col] = __float2bfloat16(v);
                }
            }
        }
    }
}

// ---------------------------------------------------------------------------
// Kernel 3: FUSED layer 1 (unchanged). 512 thr/block, 16 dst rows/block.
// ---------------------------------------------------------------------------
__global__ __launch_bounds__(512) void fused_layer1_kernel(
    const __hip_bfloat16* __restrict__ H, const int* __restrict__ col1,
    const __hip_bfloat16* __restrict__ W1T, const float* __restrict__ b1,
    float* __restrict__ out) {
    __shared__ int sc[16 * F1SZ];
    __shared__ alignas(16) short Xtile[16 * 520];
    __shared__ alignas(16) float red[8][16 * 48];

    const int tid = threadIdx.x;
    const int rowbase = blockIdx.x * 16;

    if (tid < 16 * F1SZ) {
        int i = rowbase + tid / F1SZ;
        int f = tid % F1SZ;
        sc[tid] = col1[(size_t)i * F1SZ + f];
    }
    __syncthreads();

    {
        const int r = tid >> 5;
        const int l = tid & 31;
        const unsigned short* Hs = (const unsigned short*)H;
        float a0 = 0.f, a1 = 0.f, a2 = 0.f, a3 = 0.f, a4 = 0.f, a5 = 0.f, a6 = 0.f, a7 = 0.f;
        #pragma unroll
        for (int f = 0; f < F1SZ; ++f) {
            const unsigned short* p = Hs + (size_t)sc[r * F1SZ + f] * HIDDIM + l * 8;
            ushort4 v0 = ((const ushort4*)p)[0];
            ushort4 v1 = ((const ushort4*)p)[1];
            a0 += bfu2f(v0.x); a1 += bfu2f(v0.y); a2 += bfu2f(v0.z); a3 += bfu2f(v0.w);
            a4 += bfu2f(v1.x); a5 += bfu2f(v1.y); a6 += bfu2f(v1.z); a7 += bfu2f(v1.w);
        }
        const float s = 1.0f / F1SZ;
        short8 m;
        m[0] = f2bfu(a0 * s); m[1] = f2bfu(a1 * s); m[2] = f2bfu(a2 * s); m[3] = f2bfu(a3 * s);
        m[4] = f2bfu(a4 * s); m[5] = f2bfu(a5 * s); m[6] = f2bfu(a6 * s); m[7] = f2bfu(a7 * s);
        *(short8*)&Xtile[r * 520 + l * 8] = m;
        short8 se = *(const short8*)((const short*)Hs + (size_t)(rowbase + r) * HIDDIM + l * 8);
        *(short8*)&Xtile[r * 520 + 256 + l * 8] = se;
    }
    __syncthreads();

    {
        const int wid = tid >> 6;
        const int lane = tid & 63;
        const int l15 = lane & 15;
        const int g = lane >> 4;
        const short* B = (const short*)W1T;
        f32x4 acc[3] = {};
        const int kbase = wid * 64;
        #pragma unroll
        for (int ks = 0; ks < 2; ++ks) {
            const int ka = kbase + ks * 32 + g * 8;
            short8 a = *(const short8*)&Xtile[l15 * 520 + ka];
            #pragma unroll
            for (int nt = 0; nt < 3; ++nt) {
                short8 b = *(const short8*)(B + (size_t)(nt * 16 + l15) * 512 + ka);
                acc[nt] = __builtin_amdgcn_mfma_f32_16x16x32_bf16(a, b, acc[nt], 0, 0, 0);
            }
        }
        #pragma unroll
        for (int nt = 0; nt < 3; ++nt)
            #pragma unroll
            for (int rr = 0; rr < 4; ++rr)
                red[wid][(g * 4 + rr) * 48 + nt * 16 + l15] = acc[nt][rr];
    }
    __syncthreads();

    for (int t = tid; t < 16 * 48; t += 512) {
        int rr = t / 48, c = t % 48;
        if (c < NCLSN) {
            float v = b1[c];
            #pragma unroll
            for (int w = 0; w < 8; ++w) v += red[w][t];
            out[(size_t)(rowbase + rr) * NCLSN + c] = v;
        }
    }
}

// ---------------------------------------------------------------------------
extern "C" void kernel_launch(void* const* d_in, const int* in_sizes, int n_in,
                              void* d_out, int out_size, void* d_ws, size_t ws_size,
                              hipStream_t stream) {
    const float* node_feat = (const float*)d_in[0];
    const int*   gid0      = (const int*)d_in[1];
    const int*   col0      = (const int*)d_in[2];
    const int*   col1      = (const int*)d_in[3];
    const float* Wn0       = (const float*)d_in[4];
    const float* Wr0       = (const float*)d_in[5];
    const float* b0        = (const float*)d_in[6];
    const float* Wn1       = (const float*)d_in[7];
    const float* Wr1       = (const float*)d_in[8];
    const float* b1        = (const float*)d_in[9];

    char* ws = (char*)d_ws;
    // ws layout:
    //   H     bf16 [45056][256] : 23,068,672
    //   W0T   bf16 [256][256]   :    131,072   @ 23,068,672
    //   W1T   bf16 [48][512]    :     49,152   @ 23,199,744
    //   fidx  int  [1,126,400]  :  4,505,600   @ 23,248,896
    //   sidx  int  [45,056]     :    180,224   @ 27,754,496
    //   mask  int  [45,056]     :    180,224   @ 27,934,720
    //   list  int  [45,056]     :    180,224   @ 28,114,944
    //   nlive int  [64]         :        256   @ 28,295,168
    __hip_bfloat16* H    = (__hip_bfloat16*)(ws);
    __hip_bfloat16* W0T  = (__hip_bfloat16*)(ws + 23068672);
    __hip_bfloat16* W1T  = (__hip_bfloat16*)(ws + 23199744);
    int*            fidx = (int*)(ws + 23248896);
    int*            sidx = (int*)(ws + 27754496);
    int*            mask = (int*)(ws + 27934720);
    int*            list = (int*)(ws + 28114944);
    int*            nlive= (int*)(ws + 28295168);
    float* out = (float*)d_out;

    hipLaunchKernelGGL(prep_kernel, dim3(4400), dim3(256), 0, stream,
                       Wn0, Wr0, Wn1, Wr1, gid0, col0, W0T, W1T, fidx, sidx,
                       mask, list, nlive);
    hipLaunchKernelGGL(mark_kernel, dim3((N2SZ * F1SZ + 255) / 256), dim3(256), 0, stream,
                       col1, mask, list, nlive);
    hipLaunchKernelGGL(fused_layer0_kernel, dim3(N1SZ / 16), dim3(256), 0, stream,
                       node_feat, fidx, sidx, list, nlive, W0T, b0, H);
    hipLaunchKernelGGL(fused_layer1_kernel, dim3(N2SZ / 16), dim3(512), 0, stream,
                       H, col1, W1T, b1, out);
}